// Round 8
// baseline (191.314 us; speedup 1.0000x reference)
//
#include <hip/hip_runtime.h>
#include <hip/hip_bf16.h>
#include <math.h>

#define BATCH 2
#define SEQ   2048
#define EMB   1024
#define NHEAD 16
#define DHEAD 64
#define MROWS (BATCH*SEQ)
#define QKS   2048          // Q|K packed row stride (Q cols 0..1023, K 1024..2047)

typedef unsigned int  uint;
typedef unsigned short ushort;
typedef __attribute__((ext_vector_type(8))) short short8;
typedef __attribute__((ext_vector_type(4))) float f32x4;

__device__ __forceinline__ float exp2_fast(float x) {
    return __builtin_amdgcn_exp2f(x);
}

// ---------------- bf16 helpers (HW cvt, RNE) ----------------
__device__ __forceinline__ uint pack_bf16x2(float a, float b) {
    __hip_bfloat162 h = __float22bfloat162_rn(make_float2(a, b));
    return *reinterpret_cast<uint*>(&h);
}
__device__ __forceinline__ ushort bf16_1(float a) {
    __hip_bfloat16 h = __float2bfloat16(a);
    return *reinterpret_cast<ushort*>(&h);
}

// async global->LDS, 16B per lane
__device__ __forceinline__ void gll16(const ushort* g, ushort* l) {
    __builtin_amdgcn_global_load_lds(
        (const __attribute__((address_space(1))) uint*)g,
        (__attribute__((address_space(3))) uint*)l, 16, 0, 0);
}

// ---------------- positional encoding table (fallback path) ----------------
__global__ void pos_init(float* __restrict__ pos) {
    int s = blockIdx.x;
    int d = threadIdx.x;              // 0..63
    int i = d >> 1;
    float expo  = (float)(2 * i) / (float)DHEAD;
    float scale = 1.0f / (powf(10000.0f, expo) + 1.1920928955078125e-07f);
    float ang   = (float)s * scale;
    pos[s * DHEAD + d] = (d & 1) ? cosf(ang) : sinf(ang);
}

// ------- merged prep: x->bf16 | 4 weight transposes | pos table -------------
__global__ __launch_bounds__(256) void prep_all(
    const float* __restrict__ x,
    const float* __restrict__ Wq, const float* __restrict__ Wk,
    const float* __restrict__ Wv, const float* __restrict__ Wo,
    ushort* __restrict__ xb, ushort* __restrict__ Wqkvt,
    ushort* __restrict__ Wot, float* __restrict__ pos) {
    __shared__ float tile[32][33];
    const int bid = blockIdx.x;
    if (bid < 8192) {
        int gid = bid * 256 + threadIdx.x;
        float2 v = ((const float2*)x)[gid];
        ((uint*)xb)[gid] = pack_bf16x2(v.x, v.y);
    } else if (bid < 8192 + 4096) {
        const int wb    = bid - 8192;
        const int which = wb >> 10;           // 0..3
        const int inner = wb & 1023;
        const float* W = (which == 0) ? Wq : (which == 1) ? Wk
                       : (which == 2) ? Wv : Wo;
        ushort* Wt = (which < 3) ? (Wqkvt + (size_t)which * 1024 * EMB) : Wot;
        const int c0 = (inner & 31) * 32;
        const int r0 = (inner >> 5) * 32;
        const int tx = threadIdx.x & 31;
        const int ty = threadIdx.x >> 5;
#pragma unroll
        for (int i = 0; i < 4; ++i)
            tile[ty + i * 8][tx] = W[(size_t)(r0 + ty + i * 8) * EMB + c0 + tx];
        __syncthreads();
#pragma unroll
        for (int i = 0; i < 4; ++i)
            Wt[(size_t)(c0 + ty + i * 8) * EMB + r0 + tx] = bf16_1(tile[tx][ty + i * 8]);
    } else {
        const int idx = (bid - 12288) * 256 + threadIdx.x;
        const int s = idx >> 6, d = idx & 63;
        const int i = d >> 1;
        float expo  = (float)(2 * i) / (float)DHEAD;
        float scale = 1.0f / (powf(10000.0f, expo) + 1.1920928955078125e-07f);
        float ang   = (float)s * scale;
        pos[s * DHEAD + d] = (d & 1) ? cosf(ang) : sinf(ang);
    }
}

// ------- templated bf16 MFMA GEMM: C = A @ Bt^T, TN=128, TM = TMT ----------
// v15: two TK=32 sub-tiles per barrier window. As[2][..]/Bs[2][..] indexed by
// COMPILE-TIME s (unrolled) -- unlike v13's runtime cur, alias analysis stays
// intact. Fragment addressing is byte-identical to the proven TK=32 pattern;
// staging instruction count unchanged; barriers 64 -> 32, iterations 32 -> 16.
// Tests the theory that per-iteration fixed cost (2 barriers + loop overhead)
// is the binding constraint at K=1024 (m97 ladder: same body hits 874+ TF at
// 128 iterations; we get 545 at 32).
#define TK 32
#define SCLQ (0.03125f * 1.44269504088896f)

template<int TMT>
__global__ __launch_bounds__(256) void gemm_mfma_t(
    const ushort* __restrict__ A, const ushort* __restrict__ Bt,
    void* __restrict__ Cv, ushort* __restrict__ VtOut,
    const float* __restrict__ pos, int posmode, int N, int K) {
    constexpr int MI = TMT / 32;
    __shared__ ushort As[2][TMT * TK];
    __shared__ ushort Bs[2][128 * TK];

    const int t    = threadIdx.x;
    const int lane = t & 63, w = t >> 6;
    const int quad = lane >> 4, l15 = lane & 15;
    const int bm = blockIdx.x * TMT, bn = blockIdx.y * 128;
    const int wm = (w & 1) * (TMT / 2), wn = (w >> 1) * 64;
    const int r0 = t >> 2, kp = (t & 3) * 8;

    f32x4 acc[MI][4];
#pragma unroll
    for (int mi = 0; mi < MI; ++mi)
#pragma unroll
        for (int ni = 0; ni < 4; ++ni)
            acc[mi][ni] = (f32x4){0.f, 0.f, 0.f, 0.f};

    for (int k0 = 0; k0 < K; k0 += 2 * TK) {
        __syncthreads();
#pragma unroll
        for (int s = 0; s < 2; ++s) {
#pragma unroll
            for (int i = 0; i < TMT / 64; ++i)
                gll16(A + (size_t)(bm + i * 64 + r0) * K + k0 + s * TK + kp,
                      &As[s][i * 2048 + t * 8]);
#pragma unroll
            for (int i = 0; i < 2; ++i)
                gll16(Bt + (size_t)(bn + i * 64 + r0) * K + k0 + s * TK + kp,
                      &Bs[s][i * 2048 + t * 8]);
        }
        __syncthreads();

#pragma unroll
        for (int s = 0; s < 2; ++s) {
            short8 af[MI], bfv[4];
#pragma unroll
            for (int mi = 0; mi < MI; ++mi)
                af[mi] = *(const short8*)&As[s][(wm + mi * 16 + l15) * TK + quad * 8];
#pragma unroll
            for (int ni = 0; ni < 4; ++ni)
                bfv[ni] = *(const short8*)&Bs[s][(wn + ni * 16 + l15) * TK + quad * 8];
#pragma unroll
            for (int mi = 0; mi < MI; ++mi)
#pragma unroll
                for (int ni = 0; ni < 4; ++ni)
                    acc[mi][ni] = __builtin_amdgcn_mfma_f32_16x16x32_bf16(
                        af[mi], bfv[ni], acc[mi][ni], 0, 0, 0);
        }
    }

#pragma unroll
    for (int mi = 0; mi < MI; ++mi) {
        const int row0 = bm + wm + mi * 16 + quad * 4;
#pragma unroll
        for (int ni = 0; ni < 4; ++ni) {
            const int col = bn + wn + ni * 16 + l15;
            if (!posmode) {
                float* cp = (float*)Cv + (size_t)row0 * N + col;
#pragma unroll
                for (int r = 0; r < 4; ++r)
                    cp[(size_t)r * N] = acc[mi][ni][r];
            } else if (col < 2048) {
                // rows r=0..3 are s-consecutive (row0 % 4 == 0, no 2048-wrap)
                const int s0 = row0 & (SEQ - 1);
                const float* pp = pos + s0 * DHEAD + (col & 63);
                ushort* cp = (ushort*)Cv + (size_t)row0 * QKS + col;
                const bool isq = (col < 1024);
#pragma unroll
                for (int r = 0; r < 4; ++r) {
                    float v = acc[mi][ni][r] + pp[r * DHEAD];
                    if (isq) v *= SCLQ;
                    cp[(size_t)r * QKS] = bf16_1(v);
                }
            } else {
                // V -> Vt[bh][d][s], 4 consecutive s packed
                const int hh = (col >> 6) & 15;
                const int d  = col & 63;
                const int bb = row0 >> 11;
                const int s0 = row0 & (SEQ - 1);
                uint2 u;
                u.x = pack_bf16x2(acc[mi][ni][0], acc[mi][ni][1]);
                u.y = pack_bf16x2(acc[mi][ni][2], acc[mi][ni][3]);
                *(uint2*)&VtOut[((size_t)(bb * 16 + hh) * 64 + d) * SEQ + s0] = u;
            }
        }
    }
}

// -- MFMA flash attention v12 (unchanged; best-known) -------------------------
#define LDP 72   // padded LDS row stride in ushorts

__device__ __forceinline__ void rd_frags(
    const ushort* __restrict__ S, short8 (&f0)[4], short8 (&f1)[4],
    int quad, int l15) {
#pragma unroll
    for (int g = 0; g < 4; ++g) {
        f0[g] = *(const short8*)&S[(g * 16 + l15) * LDP + quad * 8];
        f1[g] = *(const short8*)&S[(g * 16 + l15) * LDP + 32 + quad * 8];
    }
}

template<bool DIAG>
__device__ __forceinline__ void qk_tile(
    const short8 (&ak0)[4], const short8 (&ak1)[4],
    short8 aq0, short8 aq1, float (&sv)[4][4], float& pmax,
    int keyb0, int qrow, int quad) {
#pragma unroll
    for (int kg = 0; kg < 4; ++kg) {
        f32x4 a = (f32x4){0.f, 0.f, 0.f, 0.f};
        a = __builtin_amdgcn_mfma_f32_16x16x32_bf16(ak0[kg], aq0, a, 0, 0, 0);
        a = __builtin_amdgcn_mfma_f32_16x16x32_bf16(ak1[kg], aq1, a, 0, 0, 0);
        const int keyb = keyb0 + kg * 16 + quad * 4;
#pragma unroll
        for (int r = 0; r < 4; ++r) {
            float v = a[r];                 // already in log2 domain
            if (DIAG && (keyb + r > qrow)) v = -3.0e38f;
            sv[kg][r] = v;
        }
        const float m01 = fmaxf(sv[kg][0], sv[kg][1]);
        const float m23 = fmaxf(sv[kg][2], sv[kg][3]);
        pmax = fmaxf(pmax, fmaxf(m01, m23));
    }
}

// softmax + PV. l_l is a PER-LANE partial (this lane's 16 keys only);
// m_l is kept identical across the 4 lanes sharing q=l15 (invariant).
__device__ __forceinline__ void sm_pv(
    float (&sv)[4][4], float& m_l, float& l_l, float pmax,
    f32x4 (&acc)[4], ushort* __restrict__ Pw,
    const short8 (&bv0)[4], const short8 (&bv1)[4], int quad, int l15) {
    // vote on LOCAL maxima -- equivalent condition, no cross-lane reduce
    if (__any(pmax - m_l > 8.f)) {
        float pm = fmaxf(pmax, __shfl_xor(pmax, 16, 64));
        pm = fmaxf(pm, __shfl_xor(pm, 32, 64));
        const float m_new = fmaxf(m_l, pm);     // quad-consistent
        const float alpha = exp2_fast(m_l - m_new);
        m_l = m_new;
        l_l *= alpha;
        float av[4];
#pragma unroll
        for (int r = 0; r < 4; ++r) av[r] = __shfl(alpha, quad * 4 + r, 64);
#pragma unroll
        for (int nd = 0; nd < 4; ++nd)
#pragma unroll
            for (int r = 0; r < 4; ++r) acc[nd][r] *= av[r];
    }
    float rs = 0.f;
#pragma unroll
    for (int kg = 0; kg < 4; ++kg) {
#pragma unroll
        for (int r = 0; r < 4; ++r) {
            float p = exp2_fast(sv[kg][r] - m_l);
            sv[kg][r] = p;
        }
        rs += (sv[kg][0] + sv[kg][1]) + (sv[kg][2] + sv[kg][3]);
    }
    l_l += rs;                                   // per-lane partial, no shfl
    // P[q][key] write: 4 x b64 per lane (per-wave, per-tile region)
#pragma unroll
    for (int kg = 0; kg < 4; ++kg) {
        uint2 u;
        u.x = pack_bf16x2(sv[kg][0], sv[kg][1]);
        u.y = pack_bf16x2(sv[kg][2], sv[kg][3]);
        *(uint2*)&Pw[l15 * LDP + kg * 16 + quad * 4] = u;
    }
    const short8 pa0 = *(const short8*)&Pw[l15 * LDP + quad * 8];
    const short8 pa1 = *(const short8*)&Pw[l15 * LDP + 32 + quad * 8];
#pragma unroll
    for (int nd = 0; nd < 4; ++nd) {
        acc[nd] = __builtin_amdgcn_mfma_f32_16x16x32_bf16(pa0, bv0[nd], acc[nd], 0, 0, 0);
        acc[nd] = __builtin_amdgcn_mfma_f32_16x16x32_bf16(pa1, bv1[nd], acc[nd], 0, 0, 0);
    }
}

__global__ __launch_bounds__(256, 2) void attn_mfma12(
    const ushort* __restrict__ QK, const ushort* __restrict__ Vt,
    ushort* __restrict__ AOb) {
    __shared__ ushort Ks[2][64 * LDP];
    __shared__ ushort Vs[2][64 * LDP];
    __shared__ ushort Ps[2][64 * LDP];   // [tileA/tileB][...]

    // 512 blocks; bits [2:0]=bh-low (=XCD), [6:3]=pair, [8:7]=bh-high
    const int bid  = blockIdx.x;
    const int bh   = (bid & 7) | (((bid >> 7) & 3) << 3);   // 0..31
    const int pair = (bid >> 3) & 15;                       // 0..15
    const int b    = bh >> 4, hd = bh & 15;
    const int t    = threadIdx.x;
    const int lane = t & 63, w = t >> 6;
    const int quad = lane >> 4, l15 = lane & 15;
    const int wrow = w * 16;
    const int sr = t >> 2;                // staging row 0..63
    const int sc = (t & 3) * 16;          // 0,16,32,48

    const int qtA = pair;                 // short tile (<=15)
    const int qtB = 31 - pair;            // long tile (>=16), drives the loop

    const size_t qkbase = (size_t)b * SEQ * QKS + hd * 64;
    const ushort* kpb = QK + qkbase + 1024 + (size_t)sr * QKS + sc;  // + kt*64*QKS
    const ushort* vpb = Vt + ((size_t)bh * 64 + sr) * SEQ;           // + kt*64 + sc

    // Q fragments for both tiles, directly from global (pre-scaled by SCLQ)
    const ushort* qpA = QK + qkbase + (size_t)(qtA * 64 + wrow + l15) * QKS + quad * 8;
    const short8 aqA0 = *(const short8*)qpA;
    const short8 aqA1 = *(const short8*)(qpA + 32);
    const ushort* qpB = QK + qkbase + (size_t)(qtB * 64 + wrow + l15) * QKS + quad * 8;
    const short8 aqB0 = *(const short8*)qpB;
    const short8 aqB1 = *(const short8*)(qpB + 32);

    // prefetch K/V tile 0 (named scalars -> VGPRs)
    uint4 ka = *(const uint4*)kpb;
    uint4 kb = *(const uint4*)(kpb + 8);
    uint4 va = *(const uint4*)(vpb + sc);
    uint4 vb = *(const uint4*)(vpb + sc + 8);
    int cur = 0;

    f32x4 accA[4], accB[4];
#pragma unroll
    for (int nd = 0; nd < 4; ++nd) {
        accA[nd] = (f32x4){0.f, 0.f, 0.f, 0.f};
        accB[nd] = (f32x4){0.f, 0.f, 0.f, 0.f};
    }
    float mA = -3.0e38f, lA = 0.f, mB = -3.0e38f, lB = 0.f;
    const int qrowA = qtA * 64 + wrow + l15;
    const int qrowB = qtB * 64 + wrow + l15;
    ushort* PwA = &Ps[0][wrow * LDP];
    ushort* PwB = &Ps[1][wrow * LDP];

    for (int kt = 0; kt <= qtB; ++kt) {
        ushort* Kc = Ks[cur];
        ushort* Vc = Vs[cur];
        *(uint4*)&Kc[sr * LDP + sc]     = ka;
        *(uint4*)&Kc[sr * LDP + sc + 8] = kb;
        *(uint4*)&Vc[sr * LDP + sc]     = va;
        *(uint4*)&Vc[sr * LDP + sc + 8] = vb;
        __syncthreads();   // single barrier per K-tile (double-buffered)

        // next tile's prefetch: issued after the barrier, flies across compute
        const int ktn = (kt < qtB) ? kt + 1 : qtB;
        ka = *(const uint4*)(kpb + (size_t)ktn * 64 * QKS);
        kb = *(const uint4*)(kpb + (size_t)ktn * 64 * QKS + 8);
        va = *(const uint4*)(vpb + ktn * 64 + sc);
        vb = *(const uint4*)(vpb + ktn * 64 + sc + 8);

        // ---- K fragments: read ONCE, shared by both tiles ----
        short8 ak0[4], ak1[4];
        rd_frags(Kc, ak0, ak1, quad, l15);

        const bool actA = (kt <= qtA);      // block-uniform
        const int keyb0 = kt * 64;

        float svB[4][4]; float pmB = -3.0e38f;
        if (kt == qtB) qk_tile<true >(ak0, ak1, aqB0, aqB1, svB, pmB, keyb0, qrowB, quad);
        else           qk_tile<false>(ak0, ak1, aqB0, aqB1, svB, pmB, keyb0, qrowB, quad);

        float svA[4][4]; float pmA = -3.0e38f;
        if (actA) {
            if (kt == qtA) qk_tile<true >(ak0, ak1, aqA0, aqA1, svA, pmA, keyb0, qrowA, quad);
            else           qk_tile<false>(ak0, ak1, aqA0, aqA1, svA, pmA, keyb0, qrowA, quad);
        }

        // ---- V fragments: read ONCE, shared by both tiles ----
        short8 bv0[4], bv1[4];
        rd_frags(Vc, bv0, bv1, quad, l15);

        sm_pv(svB, mB, lB, pmB, accB, PwB, bv0, bv1, quad, l15);
        if (actA) sm_pv(svA, mA, lA, pmA, accA, PwA, bv0, bv1, quad, l15);

        cur ^= 1;
    }

    // ---- epilogue: quad-reduce the l partials ONCE, then write both tiles ----
    {
        float lf = lB + __shfl_xor(lB, 16, 64);
        lf += __shfl_xor(lf, 32, 64);
        float linv[4];
#pragma unroll
        for (int r = 0; r < 4; ++r) linv[r] = 1.0f / __shfl(lf, quad * 4 + r, 64);
#pragma unroll
        for (int nd = 0; nd < 4; ++nd)
#pragma unroll
            for (int r = 0; r < 4; ++r) {
                const int row = qtB * 64 + wrow + quad * 4 + r;
                AOb[(size_t)(b * SEQ + row) * EMB + hd * 64 + nd * 16 + l15] =
                    bf16_1(accB[nd][r] * linv[r]);
            }
    }
    {
        float lf = lA + __shfl_xor(lA, 16, 64);
        lf += __shfl_xor(lf, 32, 64);
        float linv[4];
#pragma unroll
        for (int r = 0; r < 4; ++r) linv[r] = 1.0f / __shfl(lf, quad * 4 + r, 64);
#pragma unroll
        for (int nd = 0; nd < 4; ++nd)
#pragma unroll
            for (int r = 0; r < 4; ++r) {
                const int row = qtA * 64 + wrow + quad * 4 + r;
                AOb[(size_t)(b * SEQ + row) * EMB + hd * 64 + nd * 16 + l15] =
                    bf16_1(accA[nd][r] * linv[r]);
            }
    }
}

// ---------------- fp32 fallback GEMM ----------------
#define BM 64
#define BN 64
#define BK 16

__global__ __launch_bounds__(256) void gemm_f32(
    const float* __restrict__ A, const float* __restrict__ B,
    float* __restrict__ C, const float* __restrict__ pos, int addpos,
    int M, int N, int K) {
    __shared__ float As[BK][BM];
    __shared__ float Bs[BK][BN];
    const int tid = threadIdx.x;
    const int bm  = blockIdx.x * BM;
    const int bn  = blockIdx.y * BN;
    const int tx  = tid & 15;
    const int ty  = tid >> 4;
    const int arow = tid >> 2;
    const int acol = (tid & 3) << 2;
    const int brow = tid >> 4;
    const int bcol = (tid & 15) << 2;
    float acc[4][4] = {{0.f}};
    const float* Aptr = A + (size_t)(bm + arow) * K + acol;
    const float* Bptr = B + (size_t)brow * N + bn + bcol;
    for (int k0 = 0; k0 < K; k0 += BK) {
        float4 av = *(const float4*)(Aptr + k0);
        float4 bv = *(const float4*)(Bptr + (size_t)k0 * N);
        __syncthreads();
        As[acol + 0][arow] = av.x;
        As[acol + 1][arow] = av.y;
        As[acol + 2][arow] = av.z;
        As[acol + 3][arow] = av.w;
        *(float4*)&Bs[brow][bcol] = bv;
        __syncthreads();
#pragma unroll
        for (int kk = 0; kk < BK; ++kk) {
            float4 a = *(const float4*)&As[kk][ty << 2];
            float4 b = *(const float4*)&Bs[kk][tx << 2];
            float aa[4] = {a.x, a.y, a.z, a.w};
            float bb[4] = {b.x, b.y, b.z, b.w};
#pragma unroll
            for (int i = 0; i < 4; ++i)
#pragma unroll
                for (int j = 0; j < 4; ++j)
                    acc[i][j] += aa[i] * bb[j];
        }
    }
#pragma unroll
    for (int i = 0; i < 4; ++i) {
        int m = bm + (ty << 2) + i;
        int n = bn + (tx << 2);
        float4 v = make_float4(acc[i][0], acc[i][1], acc[i][2], acc[i][3]);
        if (addpos) {
            int s = m & (SEQ - 1);
            int d = n & (DHEAD - 1);
            float4 p = *(const float4*)&pos[s * DHEAD + d];
            v.x += p.x; v.y += p.y; v.z += p.z; v.w += p.w;
        }
        *(float4*)&C[(size_t)m * N + n] = v;
    }
}

// ---------------- fp32 fallback attention ----------------
#define QT 128
#define KT 32
__global__ __launch_bounds__(QT) void attn_fwd(
    const float* __restrict__ Q, const float* __restrict__ Kg,
    const float* __restrict__ V, float* __restrict__ O) {
    __shared__ float Ks[KT][DHEAD];
    __shared__ float Vs[KT][DHEAD];
    const int t    = threadIdx.x;
    const int q0   = blockIdx.x * QT;
    const int bh   = blockIdx.y;
    const int b    = bh >> 4;
    const int h    = bh & 15;
    const int qrow = q0 + t;
    const size_t base = (size_t)b * SEQ * EMB + (size_t)h * DHEAD;
    float4 q4[16], o4[16];
#pragma unroll
    for (int i = 0; i < 16; ++i) {
        q4[i] = *(const float4*)&Q[base + (size_t)qrow * EMB + i * 4];
        o4[i] = make_float4(0.f, 0.f, 0.f, 0.f);
    }
    float m_i = -3.0e38f, l_i = 0.0f;
    const float scale = 0.03125f;
    const int kend = q0 + QT;
    for (int k0 = 0; k0 < kend; k0 += KT) {
        __syncthreads();
#pragma unroll
        for (int i = 0; i < 4; ++i) {
            int idx = t + i * QT;
            int r = idx >> 4;
            int c = (idx & 15) << 2;
            *(float4*)&Ks[r][c] = *(const float4*)&Kg[base + (size_t)(k0 + r) * EMB + c];
            *(float4*)&Vs[r][c] = *(const float4*)&V [base + (size_t)(k0 + r) * EMB + c];
        }
        __syncthreads();
        float sv[KT];
        float mt = m_i;
#pragma unroll
        for (int j = 0; j < KT; ++j) {
            const float4* kr = (const float4*)Ks[j];
            float dot = 0.f;
#pragma unroll
            for (int dd = 0; dd < 16; ++dd) {
                float4 kv = kr[dd];
                dot += q4[dd].x * kv.x + q4[dd].y * kv.y +
                       q4[dd].z * kv.z + q4[dd].w * kv.w;
            }
            sv[j] = (k0 + j <= qrow) ? dot * scale : -3.0e38f;
            mt = fmaxf(mt, sv[j]);
        }
        float corr = __expf(m_i - mt);
        l_i *= corr;
#pragma unroll
        for (int i = 0; i < 16; ++i) {
            o4[i].x *= corr; o4[i].y *= corr; o4[i].z *= corr; o4[i].w *= corr;
        }
#pragma unroll
        for (int j = 0; j < KT; ++j) {
            float pp = __expf(sv[j] - mt);
            l_i += pp;
            const float4* vr = (const float4*)Vs[j];
#pragma unroll
            for (int dd = 0; dd < 16; ++dd) {
                float4 vv = vr[dd];
                o4[dd].x += pp * vv.x; o4[dd].y += pp * vv.y;
                o4[dd].z += pp * vv.z; o4[dd].w += pp * vv.w;
            }
        }
        m_i = mt;
    }
    float inv = 1.0f / l_i;
#pragma unroll
    for (int i = 0; i < 16; ++i) {
        float4 v = o4[i];
        v.x *= inv; v.y *= inv; v.z *= inv; v.w *= inv;
        *(float4*)&O[base + (size_t)qrow * EMB + i * 4] = v;
    }
}

// ---------------- launch ----------------
extern "C" void kernel_launch(void* const* d_in, const int* in_sizes, int n_in,
                              void* d_out, int out_size, void* d_ws, size_t ws_size,
                              hipStream_t stream) {
    const float* x  = (const float*)d_in[0];
    const float* Wq = (const float*)d_in[1];
    const float* Wk = (const float*)d_in[2];
    const float* Wv = (const float*)d_in[3];
    const float* Wo = (const float*)d_in[4];
    float* out = (float*)d_out;

    char* ws = (char*)d_ws;
    size_t off = 0;
    float*  pos   = (float*)(ws + off);  off += (size_t)SEQ * DHEAD * 4;
    ushort* xb    = (ushort*)(ws + off); off += (size_t)MROWS * EMB * 2;
    ushort* Wqkvt = (ushort*)(ws + off); off += (size_t)3072 * EMB * 2;
    ushort* Wot   = (ushort*)(ws + off); off += (size_t)EMB * EMB * 2;
    ushort* QKb   = (ushort*)(ws + off); off += (size_t)MROWS * QKS * 2;
    ushort* Vtp   = (ushort*)(ws + off); off += (size_t)MROWS * EMB * 2;
    ushort* AOb   = (ushort*)(ws + off); off += (size_t)MROWS * EMB * 2;
    const bool use_bf16 = off <= ws_size;

    const int M = MROWS, K = EMB;

    if (use_bf16) {
        // merged prep: cvt (8192) | weight transpose (4096) | pos (512)
        prep_all<<<dim3(12800), 256, 0, stream>>>(
            x, Wq, Wk, Wv, Wo, xb, Wqkvt, Wot, pos);

        // fused QKV projection: Q/K -> QKb (stride 2048, +pos, Q*scl),
        // V -> Vtp transposed [bh][d][s]
        gemm_mfma_t<128><<<dim3(M / 128, 3072 / 128), 256, 0, stream>>>(
            xb, Wqkvt, QKb, Vtp, pos, 1, 3072, K);

        // 512 balanced paired blocks, XCD-affine decode, dual-tile interleave
        attn_mfma12<<<dim3(512), 256, 0, stream>>>(QKb, Vtp, AOb);

        // Wo GEMM: TM=64 -> 512 blocks (2/CU)
        gemm_mfma_t<64><<<dim3(M / 64, EMB / 128), 256, 0, stream>>>(
            AOb, Wot, out, nullptr, pos, 0, EMB, K);
    } else {
        // fp32 fallback
        size_t f = 0;
        float* posf = (float*)(ws + f); f += (size_t)SEQ * DHEAD * 4;
        float* Qb = (float*)(ws + f); f += (size_t)MROWS * EMB * 4;
        float* Kb = (float*)(ws + f); f += (size_t)MROWS * EMB * 4;
        float* Vb = (float*)(ws + f); f += (size_t)MROWS * EMB * 4;
        float* AO = (float*)(ws + f);
        pos_init<<<SEQ, DHEAD, 0, stream>>>(posf);
        dim3 g(M / BM, EMB / BN);
        gemm_f32<<<g, 256, 0, stream>>>(x, Wq, Qb, posf, 1, M, EMB, K);
        gemm_f32<<<g, 256, 0, stream>>>(x, Wk, Kb, posf, 1, M, EMB, K);
        gemm_f32<<<g, 256, 0, stream>>>(x, Wv, Vb, posf, 0, M, EMB, K);
        attn_fwd<<<dim3(SEQ / QT, BATCH * NHEAD), QT, 0, stream>>>(Qb, Kb, Vb, AO);
        gemm_f32<<<g, 256, 0, stream>>>(AO, Wo, out, posf, 0, M, EMB, K);
    }
}

// Round 9
// 187.791 us; speedup vs baseline: 1.0188x; 1.0188x over previous
//
#include <hip/hip_runtime.h>
#include <hip/hip_bf16.h>
#include <math.h>

#define BATCH 2
#define SEQ   2048
#define EMB   1024
#define NHEAD 16
#define DHEAD 64
#define MROWS (BATCH*SEQ)
#define QKS   2048          // Q|K packed row stride (Q cols 0..1023, K 1024..2047)

typedef unsigned int  uint;
typedef unsigned short ushort;
typedef __attribute__((ext_vector_type(8))) short short8;
typedef __attribute__((ext_vector_type(4))) float f32x4;

__device__ __forceinline__ float exp2_fast(float x) {
    return __builtin_amdgcn_exp2f(x);
}

// ---------------- bf16 helpers (HW cvt, RNE) ----------------
__device__ __forceinline__ uint pack_bf16x2(float a, float b) {
    __hip_bfloat162 h = __float22bfloat162_rn(make_float2(a, b));
    return *reinterpret_cast<uint*>(&h);
}
__device__ __forceinline__ ushort bf16_1(float a) {
    __hip_bfloat16 h = __float2bfloat16(a);
    return *reinterpret_cast<ushort*>(&h);
}

// async global->LDS, 16B per lane
__device__ __forceinline__ void gll16(const ushort* g, ushort* l) {
    __builtin_amdgcn_global_load_lds(
        (const __attribute__((address_space(1))) uint*)g,
        (__attribute__((address_space(3))) uint*)l, 16, 0, 0);
}

// ---------------- positional encoding table (fallback path) ----------------
__global__ void pos_init(float* __restrict__ pos) {
    int s = blockIdx.x;
    int d = threadIdx.x;              // 0..63
    int i = d >> 1;
    float expo  = (float)(2 * i) / (float)DHEAD;
    float scale = 1.0f / (powf(10000.0f, expo) + 1.1920928955078125e-07f);
    float ang   = (float)s * scale;
    pos[s * DHEAD + d] = (d & 1) ? cosf(ang) : sinf(ang);
}

// ------- merged prep: x->bf16 | 4 weight transposes | pos table -------------
__global__ __launch_bounds__(256) void prep_all(
    const float* __restrict__ x,
    const float* __restrict__ Wq, const float* __restrict__ Wk,
    const float* __restrict__ Wv, const float* __restrict__ Wo,
    ushort* __restrict__ xb, ushort* __restrict__ Wqkvt,
    ushort* __restrict__ Wot, float* __restrict__ pos) {
    __shared__ float tile[32][33];
    const int bid = blockIdx.x;
    if (bid < 8192) {
        int gid = bid * 256 + threadIdx.x;
        float2 v = ((const float2*)x)[gid];
        ((uint*)xb)[gid] = pack_bf16x2(v.x, v.y);
    } else if (bid < 8192 + 4096) {
        const int wb    = bid - 8192;
        const int which = wb >> 10;           // 0..3
        const int inner = wb & 1023;
        const float* W = (which == 0) ? Wq : (which == 1) ? Wk
                       : (which == 2) ? Wv : Wo;
        ushort* Wt = (which < 3) ? (Wqkvt + (size_t)which * 1024 * EMB) : Wot;
        const int c0 = (inner & 31) * 32;
        const int r0 = (inner >> 5) * 32;
        const int tx = threadIdx.x & 31;
        const int ty = threadIdx.x >> 5;
#pragma unroll
        for (int i = 0; i < 4; ++i)
            tile[ty + i * 8][tx] = W[(size_t)(r0 + ty + i * 8) * EMB + c0 + tx];
        __syncthreads();
#pragma unroll
        for (int i = 0; i < 4; ++i)
            Wt[(size_t)(c0 + ty + i * 8) * EMB + r0 + tx] = bf16_1(tile[tx][ty + i * 8]);
    } else {
        const int idx = (bid - 12288) * 256 + threadIdx.x;
        const int s = idx >> 6, d = idx & 63;
        const int i = d >> 1;
        float expo  = (float)(2 * i) / (float)DHEAD;
        float scale = 1.0f / (powf(10000.0f, expo) + 1.1920928955078125e-07f);
        float ang   = (float)s * scale;
        pos[s * DHEAD + d] = (d & 1) ? cosf(ang) : sinf(ang);
    }
}

// ------- templated bf16 MFMA GEMM: C = A @ Bt^T, TN=128, TM = TMT ----------
// v16: K-loop/staging byte-identical to v14 (proven 47.0us QKV; v13 dbuf and
// v15 2xTK both regressed -> structure is a local optimum, no more K-loop
// edits). Single delta: XCD-chunked tile remap (T1). Whole grid is co-resident
// (3 blocks/CU); default mapping put ~4 A-panels + ALL B-panels (7MB) on each
// XCD's 4MB L2 -> thrash. 1D grid, bijective decode: xcd=bid&7 owns a
// CBM x CBN tile rectangle (QKV 8x12 = 5MB, Wo 8x8 = 4MB working set).
// Staging-load drains hit L2 instead of L3/HBM.
#define TK 32
#define SCLQ (0.03125f * 1.44269504088896f)

template<int TMT>
__global__ __launch_bounds__(256) void gemm_mfma_t(
    const ushort* __restrict__ A, const ushort* __restrict__ Bt,
    void* __restrict__ Cv, ushort* __restrict__ VtOut,
    const float* __restrict__ pos, int posmode, int N, int K,
    int CBM, int CBN, int NCHM) {
    constexpr int MI = TMT / 32;
    __shared__ ushort As[TMT * TK];
    __shared__ ushort Bs[128 * TK];

    const int t    = threadIdx.x;
    const int lane = t & 63, w = t >> 6;
    const int quad = lane >> 4, l15 = lane & 15;

    // XCD-chunked bijective tile decode (pure index remap, T1)
    const int gid = blockIdx.x;
    const int xcd = gid & 7;
    const int loc = gid >> 3;                    // 0 .. CBM*CBN-1
    const int bmt = (xcd % NCHM) * CBM + (loc % CBM);
    const int bnt = (xcd / NCHM) * CBN + (loc / CBM);
    const int bm = bmt * TMT, bn = bnt * 128;

    const int wm = (w & 1) * (TMT / 2), wn = (w >> 1) * 64;
    const int r0 = t >> 2, kp = (t & 3) * 8;

    f32x4 acc[MI][4];
#pragma unroll
    for (int mi = 0; mi < MI; ++mi)
#pragma unroll
        for (int ni = 0; ni < 4; ++ni)
            acc[mi][ni] = (f32x4){0.f, 0.f, 0.f, 0.f};

    for (int k0 = 0; k0 < K; k0 += TK) {
        __syncthreads();
#pragma unroll
        for (int i = 0; i < TMT / 64; ++i)
            gll16(A + (size_t)(bm + i * 64 + r0) * K + k0 + kp, &As[i * 2048 + t * 8]);
#pragma unroll
        for (int i = 0; i < 2; ++i)
            gll16(Bt + (size_t)(bn + i * 64 + r0) * K + k0 + kp, &Bs[i * 2048 + t * 8]);
        __syncthreads();

        short8 af[MI], bfv[4];
#pragma unroll
        for (int mi = 0; mi < MI; ++mi)
            af[mi] = *(const short8*)&As[(wm + mi * 16 + l15) * TK + quad * 8];
#pragma unroll
        for (int ni = 0; ni < 4; ++ni)
            bfv[ni] = *(const short8*)&Bs[(wn + ni * 16 + l15) * TK + quad * 8];
#pragma unroll
        for (int mi = 0; mi < MI; ++mi)
#pragma unroll
            for (int ni = 0; ni < 4; ++ni)
                acc[mi][ni] = __builtin_amdgcn_mfma_f32_16x16x32_bf16(
                    af[mi], bfv[ni], acc[mi][ni], 0, 0, 0);
    }

#pragma unroll
    for (int mi = 0; mi < MI; ++mi) {
        const int row0 = bm + wm + mi * 16 + quad * 4;
#pragma unroll
        for (int ni = 0; ni < 4; ++ni) {
            const int col = bn + wn + ni * 16 + l15;
            if (!posmode) {
                float* cp = (float*)Cv + (size_t)row0 * N + col;
#pragma unroll
                for (int r = 0; r < 4; ++r)
                    cp[(size_t)r * N] = acc[mi][ni][r];
            } else if (col < 2048) {
                // rows r=0..3 are s-consecutive (row0 % 4 == 0, no 2048-wrap)
                const int s0 = row0 & (SEQ - 1);
                const float* pp = pos + s0 * DHEAD + (col & 63);
                ushort* cp = (ushort*)Cv + (size_t)row0 * QKS + col;
                const bool isq = (col < 1024);
#pragma unroll
                for (int r = 0; r < 4; ++r) {
                    float v = acc[mi][ni][r] + pp[r * DHEAD];
                    if (isq) v *= SCLQ;
                    cp[(size_t)r * QKS] = bf16_1(v);
                }
            } else {
                // V -> Vt[bh][d][s], 4 consecutive s packed
                const int hh = (col >> 6) & 15;
                const int d  = col & 63;
                const int bb = row0 >> 11;
                const int s0 = row0 & (SEQ - 1);
                uint2 u;
                u.x = pack_bf16x2(acc[mi][ni][0], acc[mi][ni][1]);
                u.y = pack_bf16x2(acc[mi][ni][2], acc[mi][ni][3]);
                *(uint2*)&VtOut[((size_t)(bb * 16 + hh) * 64 + d) * SEQ + s0] = u;
            }
        }
    }
}

// -- MFMA flash attention v12 (unchanged; best-known) -------------------------
#define LDP 72   // padded LDS row stride in ushorts

__device__ __forceinline__ void rd_frags(
    const ushort* __restrict__ S, short8 (&f0)[4], short8 (&f1)[4],
    int quad, int l15) {
#pragma unroll
    for (int g = 0; g < 4; ++g) {
        f0[g] = *(const short8*)&S[(g * 16 + l15) * LDP + quad * 8];
        f1[g] = *(const short8*)&S[(g * 16 + l15) * LDP + 32 + quad * 8];
    }
}

template<bool DIAG>
__device__ __forceinline__ void qk_tile(
    const short8 (&ak0)[4], const short8 (&ak1)[4],
    short8 aq0, short8 aq1, float (&sv)[4][4], float& pmax,
    int keyb0, int qrow, int quad) {
#pragma unroll
    for (int kg = 0; kg < 4; ++kg) {
        f32x4 a = (f32x4){0.f, 0.f, 0.f, 0.f};
        a = __builtin_amdgcn_mfma_f32_16x16x32_bf16(ak0[kg], aq0, a, 0, 0, 0);
        a = __builtin_amdgcn_mfma_f32_16x16x32_bf16(ak1[kg], aq1, a, 0, 0, 0);
        const int keyb = keyb0 + kg * 16 + quad * 4;
#pragma unroll
        for (int r = 0; r < 4; ++r) {
            float v = a[r];                 // already in log2 domain
            if (DIAG && (keyb + r > qrow)) v = -3.0e38f;
            sv[kg][r] = v;
        }
        const float m01 = fmaxf(sv[kg][0], sv[kg][1]);
        const float m23 = fmaxf(sv[kg][2], sv[kg][3]);
        pmax = fmaxf(pmax, fmaxf(m01, m23));
    }
}

// softmax + PV. l_l is a PER-LANE partial (this lane's 16 keys only);
// m_l is kept identical across the 4 lanes sharing q=l15 (invariant).
__device__ __forceinline__ void sm_pv(
    float (&sv)[4][4], float& m_l, float& l_l, float pmax,
    f32x4 (&acc)[4], ushort* __restrict__ Pw,
    const short8 (&bv0)[4], const short8 (&bv1)[4], int quad, int l15) {
    // vote on LOCAL maxima -- equivalent condition, no cross-lane reduce
    if (__any(pmax - m_l > 8.f)) {
        float pm = fmaxf(pmax, __shfl_xor(pmax, 16, 64));
        pm = fmaxf(pm, __shfl_xor(pm, 32, 64));
        const float m_new = fmaxf(m_l, pm);     // quad-consistent
        const float alpha = exp2_fast(m_l - m_new);
        m_l = m_new;
        l_l *= alpha;
        float av[4];
#pragma unroll
        for (int r = 0; r < 4; ++r) av[r] = __shfl(alpha, quad * 4 + r, 64);
#pragma unroll
        for (int nd = 0; nd < 4; ++nd)
#pragma unroll
            for (int r = 0; r < 4; ++r) acc[nd][r] *= av[r];
    }
    float rs = 0.f;
#pragma unroll
    for (int kg = 0; kg < 4; ++kg) {
#pragma unroll
        for (int r = 0; r < 4; ++r) {
            float p = exp2_fast(sv[kg][r] - m_l);
            sv[kg][r] = p;
        }
        rs += (sv[kg][0] + sv[kg][1]) + (sv[kg][2] + sv[kg][3]);
    }
    l_l += rs;                                   // per-lane partial, no shfl
    // P[q][key] write: 4 x b64 per lane (per-wave, per-tile region)
#pragma unroll
    for (int kg = 0; kg < 4; ++kg) {
        uint2 u;
        u.x = pack_bf16x2(sv[kg][0], sv[kg][1]);
        u.y = pack_bf16x2(sv[kg][2], sv[kg][3]);
        *(uint2*)&Pw[l15 * LDP + kg * 16 + quad * 4] = u;
    }
    const short8 pa0 = *(const short8*)&Pw[l15 * LDP + quad * 8];
    const short8 pa1 = *(const short8*)&Pw[l15 * LDP + 32 + quad * 8];
#pragma unroll
    for (int nd = 0; nd < 4; ++nd) {
        acc[nd] = __builtin_amdgcn_mfma_f32_16x16x32_bf16(pa0, bv0[nd], acc[nd], 0, 0, 0);
        acc[nd] = __builtin_amdgcn_mfma_f32_16x16x32_bf16(pa1, bv1[nd], acc[nd], 0, 0, 0);
    }
}

__global__ __launch_bounds__(256, 2) void attn_mfma12(
    const ushort* __restrict__ QK, const ushort* __restrict__ Vt,
    ushort* __restrict__ AOb) {
    __shared__ ushort Ks[2][64 * LDP];
    __shared__ ushort Vs[2][64 * LDP];
    __shared__ ushort Ps[2][64 * LDP];   // [tileA/tileB][...]

    // 512 blocks; bits [2:0]=bh-low (=XCD), [6:3]=pair, [8:7]=bh-high
    const int bid  = blockIdx.x;
    const int bh   = (bid & 7) | (((bid >> 7) & 3) << 3);   // 0..31
    const int pair = (bid >> 3) & 15;                       // 0..15
    const int b    = bh >> 4, hd = bh & 15;
    const int t    = threadIdx.x;
    const int lane = t & 63, w = t >> 6;
    const int quad = lane >> 4, l15 = lane & 15;
    const int wrow = w * 16;
    const int sr = t >> 2;                // staging row 0..63
    const int sc = (t & 3) * 16;          // 0,16,32,48

    const int qtA = pair;                 // short tile (<=15)
    const int qtB = 31 - pair;            // long tile (>=16), drives the loop

    const size_t qkbase = (size_t)b * SEQ * QKS + hd * 64;
    const ushort* kpb = QK + qkbase + 1024 + (size_t)sr * QKS + sc;  // + kt*64*QKS
    const ushort* vpb = Vt + ((size_t)bh * 64 + sr) * SEQ;           // + kt*64 + sc

    // Q fragments for both tiles, directly from global (pre-scaled by SCLQ)
    const ushort* qpA = QK + qkbase + (size_t)(qtA * 64 + wrow + l15) * QKS + quad * 8;
    const short8 aqA0 = *(const short8*)qpA;
    const short8 aqA1 = *(const short8*)(qpA + 32);
    const ushort* qpB = QK + qkbase + (size_t)(qtB * 64 + wrow + l15) * QKS + quad * 8;
    const short8 aqB0 = *(const short8*)qpB;
    const short8 aqB1 = *(const short8*)(qpB + 32);

    // prefetch K/V tile 0 (named scalars -> VGPRs)
    uint4 ka = *(const uint4*)kpb;
    uint4 kb = *(const uint4*)(kpb + 8);
    uint4 va = *(const uint4*)(vpb + sc);
    uint4 vb = *(const uint4*)(vpb + sc + 8);
    int cur = 0;

    f32x4 accA[4], accB[4];
#pragma unroll
    for (int nd = 0; nd < 4; ++nd) {
        accA[nd] = (f32x4){0.f, 0.f, 0.f, 0.f};
        accB[nd] = (f32x4){0.f, 0.f, 0.f, 0.f};
    }
    float mA = -3.0e38f, lA = 0.f, mB = -3.0e38f, lB = 0.f;
    const int qrowA = qtA * 64 + wrow + l15;
    const int qrowB = qtB * 64 + wrow + l15;
    ushort* PwA = &Ps[0][wrow * LDP];
    ushort* PwB = &Ps[1][wrow * LDP];

    for (int kt = 0; kt <= qtB; ++kt) {
        ushort* Kc = Ks[cur];
        ushort* Vc = Vs[cur];
        *(uint4*)&Kc[sr * LDP + sc]     = ka;
        *(uint4*)&Kc[sr * LDP + sc + 8] = kb;
        *(uint4*)&Vc[sr * LDP + sc]     = va;
        *(uint4*)&Vc[sr * LDP + sc + 8] = vb;
        __syncthreads();   // single barrier per K-tile (double-buffered)

        // next tile's prefetch: issued after the barrier, flies across compute
        const int ktn = (kt < qtB) ? kt + 1 : qtB;
        ka = *(const uint4*)(kpb + (size_t)ktn * 64 * QKS);
        kb = *(const uint4*)(kpb + (size_t)ktn * 64 * QKS + 8);
        va = *(const uint4*)(vpb + ktn * 64 + sc);
        vb = *(const uint4*)(vpb + ktn * 64 + sc + 8);

        // ---- K fragments: read ONCE, shared by both tiles ----
        short8 ak0[4], ak1[4];
        rd_frags(Kc, ak0, ak1, quad, l15);

        const bool actA = (kt <= qtA);      // block-uniform
        const int keyb0 = kt * 64;

        float svB[4][4]; float pmB = -3.0e38f;
        if (kt == qtB) qk_tile<true >(ak0, ak1, aqB0, aqB1, svB, pmB, keyb0, qrowB, quad);
        else           qk_tile<false>(ak0, ak1, aqB0, aqB1, svB, pmB, keyb0, qrowB, quad);

        float svA[4][4]; float pmA = -3.0e38f;
        if (actA) {
            if (kt == qtA) qk_tile<true >(ak0, ak1, aqA0, aqA1, svA, pmA, keyb0, qrowA, quad);
            else           qk_tile<false>(ak0, ak1, aqA0, aqA1, svA, pmA, keyb0, qrowA, quad);
        }

        // ---- V fragments: read ONCE, shared by both tiles ----
        short8 bv0[4], bv1[4];
        rd_frags(Vc, bv0, bv1, quad, l15);

        sm_pv(svB, mB, lB, pmB, accB, PwB, bv0, bv1, quad, l15);
        if (actA) sm_pv(svA, mA, lA, pmA, accA, PwA, bv0, bv1, quad, l15);

        cur ^= 1;
    }

    // ---- epilogue: quad-reduce the l partials ONCE, then write both tiles ----
    {
        float lf = lB + __shfl_xor(lB, 16, 64);
        lf += __shfl_xor(lf, 32, 64);
        float linv[4];
#pragma unroll
        for (int r = 0; r < 4; ++r) linv[r] = 1.0f / __shfl(lf, quad * 4 + r, 64);
#pragma unroll
        for (int nd = 0; nd < 4; ++nd)
#pragma unroll
            for (int r = 0; r < 4; ++r) {
                const int row = qtB * 64 + wrow + quad * 4 + r;
                AOb[(size_t)(b * SEQ + row) * EMB + hd * 64 + nd * 16 + l15] =
                    bf16_1(accB[nd][r] * linv[r]);
            }
    }
    {
        float lf = lA + __shfl_xor(lA, 16, 64);
        lf += __shfl_xor(lf, 32, 64);
        float linv[4];
#pragma unroll
        for (int r = 0; r < 4; ++r) linv[r] = 1.0f / __shfl(lf, quad * 4 + r, 64);
#pragma unroll
        for (int nd = 0; nd < 4; ++nd)
#pragma unroll
            for (int r = 0; r < 4; ++r) {
                const int row = qtA * 64 + wrow + quad * 4 + r;
                AOb[(size_t)(b * SEQ + row) * EMB + hd * 64 + nd * 16 + l15] =
                    bf16_1(accA[nd][r] * linv[r]);
            }
    }
}

// ---------------- fp32 fallback GEMM ----------------
#define BM 64
#define BN 64
#define BK 16

__global__ __launch_bounds__(256) void gemm_f32(
    const float* __restrict__ A, const float* __restrict__ B,
    float* __restrict__ C, const float* __restrict__ pos, int addpos,
    int M, int N, int K) {
    __shared__ float As[BK][BM];
    __shared__ float Bs[BK][BN];
    const int tid = threadIdx.x;
    const int bm  = blockIdx.x * BM;
    const int bn  = blockIdx.y * BN;
    const int tx  = tid & 15;
    const int ty  = tid >> 4;
    const int arow = tid >> 2;
    const int acol = (tid & 3) << 2;
    const int brow = tid >> 4;
    const int bcol = (tid & 15) << 2;
    float acc[4][4] = {{0.f}};
    const float* Aptr = A + (size_t)(bm + arow) * K + acol;
    const float* Bptr = B + (size_t)brow * N + bn + bcol;
    for (int k0 = 0; k0 < K; k0 += BK) {
        float4 av = *(const float4*)(Aptr + k0);
        float4 bv = *(const float4*)(Bptr + (size_t)k0 * N);
        __syncthreads();
        As[acol + 0][arow] = av.x;
        As[acol + 1][arow] = av.y;
        As[acol + 2][arow] = av.z;
        As[acol + 3][arow] = av.w;
        *(float4*)&Bs[brow][bcol] = bv;
        __syncthreads();
#pragma unroll
        for (int kk = 0; kk < BK; ++kk) {
            float4 a = *(const float4*)&As[kk][ty << 2];
            float4 b = *(const float4*)&Bs[kk][tx << 2];
            float aa[4] = {a.x, a.y, a.z, a.w};
            float bb[4] = {b.x, b.y, b.z, b.w};
#pragma unroll
            for (int i = 0; i < 4; ++i)
#pragma unroll
                for (int j = 0; j < 4; ++j)
                    acc[i][j] += aa[i] * bb[j];
        }
    }
#pragma unroll
    for (int i = 0; i < 4; ++i) {
        int m = bm + (ty << 2) + i;
        int n = bn + (tx << 2);
        float4 v = make_float4(acc[i][0], acc[i][1], acc[i][2], acc[i][3]);
        if (addpos) {
            int s = m & (SEQ - 1);
            int d = n & (DHEAD - 1);
            float4 p = *(const float4*)&pos[s * DHEAD + d];
            v.x += p.x; v.y += p.y; v.z += p.z; v.w += p.w;
        }
        *(float4*)&C[(size_t)m * N + n] = v;
    }
}

// ---------------- fp32 fallback attention ----------------
#define QT 128
#define KT 32
__global__ __launch_bounds__(QT) void attn_fwd(
    const float* __restrict__ Q, const float* __restrict__ Kg,
    const float* __restrict__ V, float* __restrict__ O) {
    __shared__ float Ks[KT][DHEAD];
    __shared__ float Vs[KT][DHEAD];
    const int t    = threadIdx.x;
    const int q0   = blockIdx.x * QT;
    const int bh   = blockIdx.y;
    const int b    = bh >> 4;
    const int h    = bh & 15;
    const int qrow = q0 + t;
    const size_t base = (size_t)b * SEQ * EMB + (size_t)h * DHEAD;
    float4 q4[16], o4[16];
#pragma unroll
    for (int i = 0; i < 16; ++i) {
        q4[i] = *(const float4*)&Q[base + (size_t)qrow * EMB + i * 4];
        o4[i] = make_float4(0.f, 0.f, 0.f, 0.f);
    }
    float m_i = -3.0e38f, l_i = 0.0f;
    const float scale = 0.03125f;
    const int kend = q0 + QT;
    for (int k0 = 0; k0 < kend; k0 += KT) {
        __syncthreads();
#pragma unroll
        for (int i = 0; i < 4; ++i) {
            int idx = t + i * QT;
            int r = idx >> 4;
            int c = (idx & 15) << 2;
            *(float4*)&Ks[r][c] = *(const float4*)&Kg[base + (size_t)(k0 + r) * EMB + c];
            *(float4*)&Vs[r][c] = *(const float4*)&V [base + (size_t)(k0 + r) * EMB + c];
        }
        __syncthreads();
        float sv[KT];
        float mt = m_i;
#pragma unroll
        for (int j = 0; j < KT; ++j) {
            const float4* kr = (const float4*)Ks[j];
            float dot = 0.f;
#pragma unroll
            for (int dd = 0; dd < 16; ++dd) {
                float4 kv = kr[dd];
                dot += q4[dd].x * kv.x + q4[dd].y * kv.y +
                       q4[dd].z * kv.z + q4[dd].w * kv.w;
            }
            sv[j] = (k0 + j <= qrow) ? dot * scale : -3.0e38f;
            mt = fmaxf(mt, sv[j]);
        }
        float corr = __expf(m_i - mt);
        l_i *= corr;
#pragma unroll
        for (int i = 0; i < 16; ++i) {
            o4[i].x *= corr; o4[i].y *= corr; o4[i].z *= corr; o4[i].w *= corr;
        }
#pragma unroll
        for (int j = 0; j < KT; ++j) {
            float pp = __expf(sv[j] - mt);
            l_i += pp;
            const float4* vr = (const float4*)Vs[j];
#pragma unroll
            for (int dd = 0; dd < 16; ++dd) {
                float4 vv = vr[dd];
                o4[dd].x += pp * vv.x; o4[dd].y += pp * vv.y;
                o4[dd].z += pp * vv.z; o4[dd].w += pp * vv.w;
            }
        }
        m_i = mt;
    }
    float inv = 1.0f / l_i;
#pragma unroll
    for (int i = 0; i < 16; ++i) {
        float4 v = o4[i];
        v.x *= inv; v.y *= inv; v.z *= inv; v.w *= inv;
        *(float4*)&O[base + (size_t)qrow * EMB + i * 4] = v;
    }
}

// ---------------- launch ----------------
extern "C" void kernel_launch(void* const* d_in, const int* in_sizes, int n_in,
                              void* d_out, int out_size, void* d_ws, size_t ws_size,
                              hipStream_t stream) {
    const float* x  = (const float*)d_in[0];
    const float* Wq = (const float*)d_in[1];
    const float* Wk = (const float*)d_in[2];
    const float* Wv = (const float*)d_in[3];
    const float* Wo = (const float*)d_in[4];
    float* out = (float*)d_out;

    char* ws = (char*)d_ws;
    size_t off = 0;
    float*  pos   = (float*)(ws + off);  off += (size_t)SEQ * DHEAD * 4;
    ushort* xb    = (ushort*)(ws + off); off += (size_t)MROWS * EMB * 2;
    ushort* Wqkvt = (ushort*)(ws + off); off += (size_t)3072 * EMB * 2;
    ushort* Wot   = (ushort*)(ws + off); off += (size_t)EMB * EMB * 2;
    ushort* QKb   = (ushort*)(ws + off); off += (size_t)MROWS * QKS * 2;
    ushort* Vtp   = (ushort*)(ws + off); off += (size_t)MROWS * EMB * 2;
    ushort* AOb   = (ushort*)(ws + off); off += (size_t)MROWS * EMB * 2;
    const bool use_bf16 = off <= ws_size;

    const int M = MROWS, K = EMB;

    if (use_bf16) {
        // merged prep: cvt (8192) | weight transpose (4096) | pos (512)
        prep_all<<<dim3(12800), 256, 0, stream>>>(
            x, Wq, Wk, Wv, Wo, xb, Wqkvt, Wot, pos);

        // fused QKV projection (1D grid, XCD-chunked 8x12 tile rects):
        // Q/K -> QKb (stride 2048, +pos, Q*scl), V -> Vtp transposed
        gemm_mfma_t<128><<<dim3(768), 256, 0, stream>>>(
            xb, Wqkvt, QKb, Vtp, pos, 1, 3072, K, 8, 12, 4);

        // 512 balanced paired blocks, XCD-affine decode, dual-tile interleave
        attn_mfma12<<<dim3(512), 256, 0, stream>>>(QKb, Vtp, AOb);

        // Wo GEMM: 1D grid, XCD-chunked 8x8 tile rects (4MB/XCD working set)
        gemm_mfma_t<64><<<dim3(512), 256, 0, stream>>>(
            AOb, Wot, out, nullptr, pos, 0, EMB, K, 8, 8, 8);
    } else {
        // fp32 fallback
        size_t f = 0;
        float* posf = (float*)(ws + f); f += (size_t)SEQ * DHEAD * 4;
        float* Qb = (float*)(ws + f); f += (size_t)MROWS * EMB * 4;
        float* Kb = (float*)(ws + f); f += (size_t)MROWS * EMB * 4;
        float* Vb = (float*)(ws + f); f += (size_t)MROWS * EMB * 4;
        float* AO = (float*)(ws + f);
        pos_init<<<SEQ, DHEAD, 0, stream>>>(posf);
        dim3 g(M / BM, EMB / BN);
        gemm_f32<<<g, 256, 0, stream>>>(x, Wq, Qb, posf, 1, M, EMB, K);
        gemm_f32<<<g, 256, 0, stream>>>(x, Wk, Kb, posf, 1, M, EMB, K);
        gemm_f32<<<g, 256, 0, stream>>>(x, Wv, Vb, posf, 0, M, EMB, K);
        attn_fwd<<<dim3(SEQ / QT, BATCH * NHEAD), QT, 0, stream>>>(Qb, Kb, Vb, AO);
        gemm_f32<<<g, 256, 0, stream>>>(AO, Wo, out, posf, 0, M, EMB, K);
    }
}

// Round 10
// 183.666 us; speedup vs baseline: 1.0416x; 1.0225x over previous
//
#include <hip/hip_runtime.h>
#include <hip/hip_bf16.h>
#include <math.h>

#define BATCH 2
#define SEQ   2048
#define EMB   1024
#define NHEAD 16
#define DHEAD 64
#define MROWS (BATCH*SEQ)
#define QKS   2048          // Q|K packed row stride (Q cols 0..1023, K 1024..2047)

typedef unsigned int  uint;
typedef unsigned short ushort;
typedef __attribute__((ext_vector_type(8))) short short8;
typedef __attribute__((ext_vector_type(4))) float f32x4;

__device__ __forceinline__ float exp2_fast(float x) {
    return __builtin_amdgcn_exp2f(x);
}

// ---------------- bf16 helpers (HW cvt, RNE) ----------------
__device__ __forceinline__ uint pack_bf16x2(float a, float b) {
    __hip_bfloat162 h = __float22bfloat162_rn(make_float2(a, b));
    return *reinterpret_cast<uint*>(&h);
}
__device__ __forceinline__ ushort bf16_1(float a) {
    __hip_bfloat16 h = __float2bfloat16(a);
    return *reinterpret_cast<ushort*>(&h);
}

// async global->LDS, 16B per lane
__device__ __forceinline__ void gll16(const ushort* g, ushort* l) {
    __builtin_amdgcn_global_load_lds(
        (const __attribute__((address_space(1))) uint*)g,
        (__attribute__((address_space(3))) uint*)l, 16, 0, 0);
}

// ---------------- positional encoding table (fallback path) ----------------
__global__ void pos_init(float* __restrict__ pos) {
    int s = blockIdx.x;
    int d = threadIdx.x;              // 0..63
    int i = d >> 1;
    float expo  = (float)(2 * i) / (float)DHEAD;
    float scale = 1.0f / (powf(10000.0f, expo) + 1.1920928955078125e-07f);
    float ang   = (float)s * scale;
    pos[s * DHEAD + d] = (d & 1) ? cosf(ang) : sinf(ang);
}

// ------- merged prep: x->bf16 (float4) | 4 weight transposes | pos table ----
// v17: x-cvt widened to float4 (16B/lane, G13); cvt grid 8192 -> 4096 blocks.
__global__ __launch_bounds__(256) void prep_all(
    const float* __restrict__ x,
    const float* __restrict__ Wq, const float* __restrict__ Wk,
    const float* __restrict__ Wv, const float* __restrict__ Wo,
    ushort* __restrict__ xb, ushort* __restrict__ Wqkvt,
    ushort* __restrict__ Wot, float* __restrict__ pos) {
    __shared__ float tile[32][33];
    const int bid = blockIdx.x;
    if (bid < 4096) {
        // fp32 -> bf16 rowmajor, 4 elems/thread (4096*256*4 = 4M elems)
        int gid = bid * 256 + threadIdx.x;
        float4 v = ((const float4*)x)[gid];
        uint2 u;
        u.x = pack_bf16x2(v.x, v.y);
        u.y = pack_bf16x2(v.z, v.w);
        ((uint2*)xb)[gid] = u;
    } else if (bid < 4096 + 4096) {
        const int wb    = bid - 4096;
        const int which = wb >> 10;           // 0..3
        const int inner = wb & 1023;
        const float* W = (which == 0) ? Wq : (which == 1) ? Wk
                       : (which == 2) ? Wv : Wo;
        ushort* Wt = (which < 3) ? (Wqkvt + (size_t)which * 1024 * EMB) : Wot;
        const int c0 = (inner & 31) * 32;
        const int r0 = (inner >> 5) * 32;
        const int tx = threadIdx.x & 31;
        const int ty = threadIdx.x >> 5;
#pragma unroll
        for (int i = 0; i < 4; ++i)
            tile[ty + i * 8][tx] = W[(size_t)(r0 + ty + i * 8) * EMB + c0 + tx];
        __syncthreads();
#pragma unroll
        for (int i = 0; i < 4; ++i)
            Wt[(size_t)(c0 + ty + i * 8) * EMB + r0 + tx] = bf16_1(tile[tx][ty + i * 8]);
    } else {
        const int idx = (bid - 8192) * 256 + threadIdx.x;
        const int s = idx >> 6, d = idx & 63;
        const int i = d >> 1;
        float expo  = (float)(2 * i) / (float)DHEAD;
        float scale = 1.0f / (powf(10000.0f, expo) + 1.1920928955078125e-07f);
        float ang   = (float)s * scale;
        pos[s * DHEAD + d] = (d & 1) ? cosf(ang) : sinf(ang);
    }
}

// ------- templated bf16 MFMA GEMM: C = A @ Bt^T, TN=128, TM = TMT ----------
// v17 == v14 (proven 47.0us QKV twice). GEMM K-loop is FROZEN: v13 explicit
// dbuf (-49%), v15 2xTK (-54%), v16 XCD-chunk (-4%; FETCH -26% but drain is
// L2-LATENCY-bound, not traffic-bound) all regressed. The single-buffer
// {stage -> drain -> compute} cadence at 3 blocks/CU is a local optimum;
// breaking past ~545 TF requires the 8-phase 256-sq schedule (192-block grid
// here -> 75% CU coverage), a full-template port, not an incremental edit.
#define TK 32
#define SCLQ (0.03125f * 1.44269504088896f)

template<int TMT>
__global__ __launch_bounds__(256) void gemm_mfma_t(
    const ushort* __restrict__ A, const ushort* __restrict__ Bt,
    void* __restrict__ Cv, ushort* __restrict__ VtOut,
    const float* __restrict__ pos, int posmode, int N, int K) {
    constexpr int MI = TMT / 32;
    __shared__ ushort As[TMT * TK];
    __shared__ ushort Bs[128 * TK];

    const int t    = threadIdx.x;
    const int lane = t & 63, w = t >> 6;
    const int quad = lane >> 4, l15 = lane & 15;
    const int bm = blockIdx.x * TMT, bn = blockIdx.y * 128;
    const int wm = (w & 1) * (TMT / 2), wn = (w >> 1) * 64;
    const int r0 = t >> 2, kp = (t & 3) * 8;

    f32x4 acc[MI][4];
#pragma unroll
    for (int mi = 0; mi < MI; ++mi)
#pragma unroll
        for (int ni = 0; ni < 4; ++ni)
            acc[mi][ni] = (f32x4){0.f, 0.f, 0.f, 0.f};

    for (int k0 = 0; k0 < K; k0 += TK) {
        __syncthreads();
#pragma unroll
        for (int i = 0; i < TMT / 64; ++i)
            gll16(A + (size_t)(bm + i * 64 + r0) * K + k0 + kp, &As[i * 2048 + t * 8]);
#pragma unroll
        for (int i = 0; i < 2; ++i)
            gll16(Bt + (size_t)(bn + i * 64 + r0) * K + k0 + kp, &Bs[i * 2048 + t * 8]);
        __syncthreads();

        short8 af[MI], bfv[4];
#pragma unroll
        for (int mi = 0; mi < MI; ++mi)
            af[mi] = *(const short8*)&As[(wm + mi * 16 + l15) * TK + quad * 8];
#pragma unroll
        for (int ni = 0; ni < 4; ++ni)
            bfv[ni] = *(const short8*)&Bs[(wn + ni * 16 + l15) * TK + quad * 8];
#pragma unroll
        for (int mi = 0; mi < MI; ++mi)
#pragma unroll
            for (int ni = 0; ni < 4; ++ni)
                acc[mi][ni] = __builtin_amdgcn_mfma_f32_16x16x32_bf16(
                    af[mi], bfv[ni], acc[mi][ni], 0, 0, 0);
    }

#pragma unroll
    for (int mi = 0; mi < MI; ++mi) {
        const int row0 = bm + wm + mi * 16 + quad * 4;
#pragma unroll
        for (int ni = 0; ni < 4; ++ni) {
            const int col = bn + wn + ni * 16 + l15;
            if (!posmode) {
                float* cp = (float*)Cv + (size_t)row0 * N + col;
#pragma unroll
                for (int r = 0; r < 4; ++r)
                    cp[(size_t)r * N] = acc[mi][ni][r];
            } else if (col < 2048) {
                // rows r=0..3 are s-consecutive (row0 % 4 == 0, no 2048-wrap)
                const int s0 = row0 & (SEQ - 1);
                const float* pp = pos + s0 * DHEAD + (col & 63);
                ushort* cp = (ushort*)Cv + (size_t)row0 * QKS + col;
                const bool isq = (col < 1024);
#pragma unroll
                for (int r = 0; r < 4; ++r) {
                    float v = acc[mi][ni][r] + pp[r * DHEAD];
                    if (isq) v *= SCLQ;
                    cp[(size_t)r * QKS] = bf16_1(v);
                }
            } else {
                // V -> Vt[bh][d][s], 4 consecutive s packed
                const int hh = (col >> 6) & 15;
                const int d  = col & 63;
                const int bb = row0 >> 11;
                const int s0 = row0 & (SEQ - 1);
                uint2 u;
                u.x = pack_bf16x2(acc[mi][ni][0], acc[mi][ni][1]);
                u.y = pack_bf16x2(acc[mi][ni][2], acc[mi][ni][3]);
                *(uint2*)&VtOut[((size_t)(bb * 16 + hh) * 64 + d) * SEQ + s0] = u;
            }
        }
    }
}

// -- MFMA flash attention v12 (unchanged; best-known) -------------------------
#define LDP 72   // padded LDS row stride in ushorts

__device__ __forceinline__ void rd_frags(
    const ushort* __restrict__ S, short8 (&f0)[4], short8 (&f1)[4],
    int quad, int l15) {
#pragma unroll
    for (int g = 0; g < 4; ++g) {
        f0[g] = *(const short8*)&S[(g * 16 + l15) * LDP + quad * 8];
        f1[g] = *(const short8*)&S[(g * 16 + l15) * LDP + 32 + quad * 8];
    }
}

template<bool DIAG>
__device__ __forceinline__ void qk_tile(
    const short8 (&ak0)[4], const short8 (&ak1)[4],
    short8 aq0, short8 aq1, float (&sv)[4][4], float& pmax,
    int keyb0, int qrow, int quad) {
#pragma unroll
    for (int kg = 0; kg < 4; ++kg) {
        f32x4 a = (f32x4){0.f, 0.f, 0.f, 0.f};
        a = __builtin_amdgcn_mfma_f32_16x16x32_bf16(ak0[kg], aq0, a, 0, 0, 0);
        a = __builtin_amdgcn_mfma_f32_16x16x32_bf16(ak1[kg], aq1, a, 0, 0, 0);
        const int keyb = keyb0 + kg * 16 + quad * 4;
#pragma unroll
        for (int r = 0; r < 4; ++r) {
            float v = a[r];                 // already in log2 domain
            if (DIAG && (keyb + r > qrow)) v = -3.0e38f;
            sv[kg][r] = v;
        }
        const float m01 = fmaxf(sv[kg][0], sv[kg][1]);
        const float m23 = fmaxf(sv[kg][2], sv[kg][3]);
        pmax = fmaxf(pmax, fmaxf(m01, m23));
    }
}

// softmax + PV. l_l is a PER-LANE partial (this lane's 16 keys only);
// m_l is kept identical across the 4 lanes sharing q=l15 (invariant).
__device__ __forceinline__ void sm_pv(
    float (&sv)[4][4], float& m_l, float& l_l, float pmax,
    f32x4 (&acc)[4], ushort* __restrict__ Pw,
    const short8 (&bv0)[4], const short8 (&bv1)[4], int quad, int l15) {
    // vote on LOCAL maxima -- equivalent condition, no cross-lane reduce
    if (__any(pmax - m_l > 8.f)) {
        float pm = fmaxf(pmax, __shfl_xor(pmax, 16, 64));
        pm = fmaxf(pm, __shfl_xor(pm, 32, 64));
        const float m_new = fmaxf(m_l, pm);     // quad-consistent
        const float alpha = exp2_fast(m_l - m_new);
        m_l = m_new;
        l_l *= alpha;
        float av[4];
#pragma unroll
        for (int r = 0; r < 4; ++r) av[r] = __shfl(alpha, quad * 4 + r, 64);
#pragma unroll
        for (int nd = 0; nd < 4; ++nd)
#pragma unroll
            for (int r = 0; r < 4; ++r) acc[nd][r] *= av[r];
    }
    float rs = 0.f;
#pragma unroll
    for (int kg = 0; kg < 4; ++kg) {
#pragma unroll
        for (int r = 0; r < 4; ++r) {
            float p = exp2_fast(sv[kg][r] - m_l);
            sv[kg][r] = p;
        }
        rs += (sv[kg][0] + sv[kg][1]) + (sv[kg][2] + sv[kg][3]);
    }
    l_l += rs;                                   // per-lane partial, no shfl
    // P[q][key] write: 4 x b64 per lane (per-wave, per-tile region)
#pragma unroll
    for (int kg = 0; kg < 4; ++kg) {
        uint2 u;
        u.x = pack_bf16x2(sv[kg][0], sv[kg][1]);
        u.y = pack_bf16x2(sv[kg][2], sv[kg][3]);
        *(uint2*)&Pw[l15 * LDP + kg * 16 + quad * 4] = u;
    }
    const short8 pa0 = *(const short8*)&Pw[l15 * LDP + quad * 8];
    const short8 pa1 = *(const short8*)&Pw[l15 * LDP + 32 + quad * 8];
#pragma unroll
    for (int nd = 0; nd < 4; ++nd) {
        acc[nd] = __builtin_amdgcn_mfma_f32_16x16x32_bf16(pa0, bv0[nd], acc[nd], 0, 0, 0);
        acc[nd] = __builtin_amdgcn_mfma_f32_16x16x32_bf16(pa1, bv1[nd], acc[nd], 0, 0, 0);
    }
}

__global__ __launch_bounds__(256, 2) void attn_mfma12(
    const ushort* __restrict__ QK, const ushort* __restrict__ Vt,
    ushort* __restrict__ AOb) {
    __shared__ ushort Ks[2][64 * LDP];
    __shared__ ushort Vs[2][64 * LDP];
    __shared__ ushort Ps[2][64 * LDP];   // [tileA/tileB][...]

    // 512 blocks; bits [2:0]=bh-low (=XCD), [6:3]=pair, [8:7]=bh-high
    const int bid  = blockIdx.x;
    const int bh   = (bid & 7) | (((bid >> 7) & 3) << 3);   // 0..31
    const int pair = (bid >> 3) & 15;                       // 0..15
    const int b    = bh >> 4, hd = bh & 15;
    const int t    = threadIdx.x;
    const int lane = t & 63, w = t >> 6;
    const int quad = lane >> 4, l15 = lane & 15;
    const int wrow = w * 16;
    const int sr = t >> 2;                // staging row 0..63
    const int sc = (t & 3) * 16;          // 0,16,32,48

    const int qtA = pair;                 // short tile (<=15)
    const int qtB = 31 - pair;            // long tile (>=16), drives the loop

    const size_t qkbase = (size_t)b * SEQ * QKS + hd * 64;
    const ushort* kpb = QK + qkbase + 1024 + (size_t)sr * QKS + sc;  // + kt*64*QKS
    const ushort* vpb = Vt + ((size_t)bh * 64 + sr) * SEQ;           // + kt*64 + sc

    // Q fragments for both tiles, directly from global (pre-scaled by SCLQ)
    const ushort* qpA = QK + qkbase + (size_t)(qtA * 64 + wrow + l15) * QKS + quad * 8;
    const short8 aqA0 = *(const short8*)qpA;
    const short8 aqA1 = *(const short8*)(qpA + 32);
    const ushort* qpB = QK + qkbase + (size_t)(qtB * 64 + wrow + l15) * QKS + quad * 8;
    const short8 aqB0 = *(const short8*)qpB;
    const short8 aqB1 = *(const short8*)(qpB + 32);

    // prefetch K/V tile 0 (named scalars -> VGPRs)
    uint4 ka = *(const uint4*)kpb;
    uint4 kb = *(const uint4*)(kpb + 8);
    uint4 va = *(const uint4*)(vpb + sc);
    uint4 vb = *(const uint4*)(vpb + sc + 8);
    int cur = 0;

    f32x4 accA[4], accB[4];
#pragma unroll
    for (int nd = 0; nd < 4; ++nd) {
        accA[nd] = (f32x4){0.f, 0.f, 0.f, 0.f};
        accB[nd] = (f32x4){0.f, 0.f, 0.f, 0.f};
    }
    float mA = -3.0e38f, lA = 0.f, mB = -3.0e38f, lB = 0.f;
    const int qrowA = qtA * 64 + wrow + l15;
    const int qrowB = qtB * 64 + wrow + l15;
    ushort* PwA = &Ps[0][wrow * LDP];
    ushort* PwB = &Ps[1][wrow * LDP];

    for (int kt = 0; kt <= qtB; ++kt) {
        ushort* Kc = Ks[cur];
        ushort* Vc = Vs[cur];
        *(uint4*)&Kc[sr * LDP + sc]     = ka;
        *(uint4*)&Kc[sr * LDP + sc + 8] = kb;
        *(uint4*)&Vc[sr * LDP + sc]     = va;
        *(uint4*)&Vc[sr * LDP + sc + 8] = vb;
        __syncthreads();   // single barrier per K-tile (double-buffered)

        // next tile's prefetch: issued after the barrier, flies across compute
        const int ktn = (kt < qtB) ? kt + 1 : qtB;
        ka = *(const uint4*)(kpb + (size_t)ktn * 64 * QKS);
        kb = *(const uint4*)(kpb + (size_t)ktn * 64 * QKS + 8);
        va = *(const uint4*)(vpb + ktn * 64 + sc);
        vb = *(const uint4*)(vpb + ktn * 64 + sc + 8);

        // ---- K fragments: read ONCE, shared by both tiles ----
        short8 ak0[4], ak1[4];
        rd_frags(Kc, ak0, ak1, quad, l15);

        const bool actA = (kt <= qtA);      // block-uniform
        const int keyb0 = kt * 64;

        float svB[4][4]; float pmB = -3.0e38f;
        if (kt == qtB) qk_tile<true >(ak0, ak1, aqB0, aqB1, svB, pmB, keyb0, qrowB, quad);
        else           qk_tile<false>(ak0, ak1, aqB0, aqB1, svB, pmB, keyb0, qrowB, quad);

        float svA[4][4]; float pmA = -3.0e38f;
        if (actA) {
            if (kt == qtA) qk_tile<true >(ak0, ak1, aqA0, aqA1, svA, pmA, keyb0, qrowA, quad);
            else           qk_tile<false>(ak0, ak1, aqA0, aqA1, svA, pmA, keyb0, qrowA, quad);
        }

        // ---- V fragments: read ONCE, shared by both tiles ----
        short8 bv0[4], bv1[4];
        rd_frags(Vc, bv0, bv1, quad, l15);

        sm_pv(svB, mB, lB, pmB, accB, PwB, bv0, bv1, quad, l15);
        if (actA) sm_pv(svA, mA, lA, pmA, accA, PwA, bv0, bv1, quad, l15);

        cur ^= 1;
    }

    // ---- epilogue: quad-reduce the l partials ONCE, then write both tiles ----
    {
        float lf = lB + __shfl_xor(lB, 16, 64);
        lf += __shfl_xor(lf, 32, 64);
        float linv[4];
#pragma unroll
        for (int r = 0; r < 4; ++r) linv[r] = 1.0f / __shfl(lf, quad * 4 + r, 64);
#pragma unroll
        for (int nd = 0; nd < 4; ++nd)
#pragma unroll
            for (int r = 0; r < 4; ++r) {
                const int row = qtB * 64 + wrow + quad * 4 + r;
                AOb[(size_t)(b * SEQ + row) * EMB + hd * 64 + nd * 16 + l15] =
                    bf16_1(accB[nd][r] * linv[r]);
            }
    }
    {
        float lf = lA + __shfl_xor(lA, 16, 64);
        lf += __shfl_xor(lf, 32, 64);
        float linv[4];
#pragma unroll
        for (int r = 0; r < 4; ++r) linv[r] = 1.0f / __shfl(lf, quad * 4 + r, 64);
#pragma unroll
        for (int nd = 0; nd < 4; ++nd)
#pragma unroll
            for (int r = 0; r < 4; ++r) {
                const int row = qtA * 64 + wrow + quad * 4 + r;
                AOb[(size_t)(b * SEQ + row) * EMB + hd * 64 + nd * 16 + l15] =
                    bf16_1(accA[nd][r] * linv[r]);
            }
    }
}

// ---------------- fp32 fallback GEMM ----------------
#define BM 64
#define BN 64
#define BK 16

__global__ __launch_bounds__(256) void gemm_f32(
    const float* __restrict__ A, const float* __restrict__ B,
    float* __restrict__ C, const float* __restrict__ pos, int addpos,
    int M, int N, int K) {
    __shared__ float As[BK][BM];
    __shared__ float Bs[BK][BN];
    const int tid = threadIdx.x;
    const int bm  = blockIdx.x * BM;
    const int bn  = blockIdx.y * BN;
    const int tx  = tid & 15;
    const int ty  = tid >> 4;
    const int arow = tid >> 2;
    const int acol = (tid & 3) << 2;
    const int brow = tid >> 4;
    const int bcol = (tid & 15) << 2;
    float acc[4][4] = {{0.f}};
    const float* Aptr = A + (size_t)(bm + arow) * K + acol;
    const float* Bptr = B + (size_t)brow * N + bn + bcol;
    for (int k0 = 0; k0 < K; k0 += BK) {
        float4 av = *(const float4*)(Aptr + k0);
        float4 bv = *(const float4*)(Bptr + (size_t)k0 * N);
        __syncthreads();
        As[acol + 0][arow] = av.x;
        As[acol + 1][arow] = av.y;
        As[acol + 2][arow] = av.z;
        As[acol + 3][arow] = av.w;
        *(float4*)&Bs[brow][bcol] = bv;
        __syncthreads();
#pragma unroll
        for (int kk = 0; kk < BK; ++kk) {
            float4 a = *(const float4*)&As[kk][ty << 2];
            float4 b = *(const float4*)&Bs[kk][tx << 2];
            float aa[4] = {a.x, a.y, a.z, a.w};
            float bb[4] = {b.x, b.y, b.z, b.w};
#pragma unroll
            for (int i = 0; i < 4; ++i)
#pragma unroll
                for (int j = 0; j < 4; ++j)
                    acc[i][j] += aa[i] * bb[j];
        }
    }
#pragma unroll
    for (int i = 0; i < 4; ++i) {
        int m = bm + (ty << 2) + i;
        int n = bn + (tx << 2);
        float4 v = make_float4(acc[i][0], acc[i][1], acc[i][2], acc[i][3]);
        if (addpos) {
            int s = m & (SEQ - 1);
            int d = n & (DHEAD - 1);
            float4 p = *(const float4*)&pos[s * DHEAD + d];
            v.x += p.x; v.y += p.y; v.z += p.z; v.w += p.w;
        }
        *(float4*)&C[(size_t)m * N + n] = v;
    }
}

// ---------------- fp32 fallback attention ----------------
#define QT 128
#define KT 32
__global__ __launch_bounds__(QT) void attn_fwd(
    const float* __restrict__ Q, const float* __restrict__ Kg,
    const float* __restrict__ V, float* __restrict__ O) {
    __shared__ float Ks[KT][DHEAD];
    __shared__ float Vs[KT][DHEAD];
    const int t    = threadIdx.x;
    const int q0   = blockIdx.x * QT;
    const int bh   = blockIdx.y;
    const int b    = bh >> 4;
    const int h    = bh & 15;
    const int qrow = q0 + t;
    const size_t base = (size_t)b * SEQ * EMB + (size_t)h * DHEAD;
    float4 q4[16], o4[16];
#pragma unroll
    for (int i = 0; i < 16; ++i) {
        q4[i] = *(const float4*)&Q[base + (size_t)qrow * EMB + i * 4];
        o4[i] = make_float4(0.f, 0.f, 0.f, 0.f);
    }
    float m_i = -3.0e38f, l_i = 0.0f;
    const float scale = 0.03125f;
    const int kend = q0 + QT;
    for (int k0 = 0; k0 < kend; k0 += KT) {
        __syncthreads();
#pragma unroll
        for (int i = 0; i < 4; ++i) {
            int idx = t + i * QT;
            int r = idx >> 4;
            int c = (idx & 15) << 2;
            *(float4*)&Ks[r][c] = *(const float4*)&Kg[base + (size_t)(k0 + r) * EMB + c];
            *(float4*)&Vs[r][c] = *(const float4*)&V [base + (size_t)(k0 + r) * EMB + c];
        }
        __syncthreads();
        float sv[KT];
        float mt = m_i;
#pragma unroll
        for (int j = 0; j < KT; ++j) {
            const float4* kr = (const float4*)Ks[j];
            float dot = 0.f;
#pragma unroll
            for (int dd = 0; dd < 16; ++dd) {
                float4 kv = kr[dd];
                dot += q4[dd].x * kv.x + q4[dd].y * kv.y +
                       q4[dd].z * kv.z + q4[dd].w * kv.w;
            }
            sv[j] = (k0 + j <= qrow) ? dot * scale : -3.0e38f;
            mt = fmaxf(mt, sv[j]);
        }
        float corr = __expf(m_i - mt);
        l_i *= corr;
#pragma unroll
        for (int i = 0; i < 16; ++i) {
            o4[i].x *= corr; o4[i].y *= corr; o4[i].z *= corr; o4[i].w *= corr;
        }
#pragma unroll
        for (int j = 0; j < KT; ++j) {
            float pp = __expf(sv[j] - mt);
            l_i += pp;
            const float4* vr = (const float4*)Vs[j];
#pragma unroll
            for (int dd = 0; dd < 16; ++dd) {
                float4 vv = vr[dd];
                o4[dd].x += pp * vv.x; o4[dd].y += pp * vv.y;
                o4[dd].z += pp * vv.z; o4[dd].w += pp * vv.w;
            }
        }
        m_i = mt;
    }
    float inv = 1.0f / l_i;
#pragma unroll
    for (int i = 0; i < 16; ++i) {
        float4 v = o4[i];
        v.x *= inv; v.y *= inv; v.z *= inv; v.w *= inv;
        *(float4*)&O[base + (size_t)qrow * EMB + i * 4] = v;
    }
}

// ---------------- launch ----------------
extern "C" void kernel_launch(void* const* d_in, const int* in_sizes, int n_in,
                              void* d_out, int out_size, void* d_ws, size_t ws_size,
                              hipStream_t stream) {
    const float* x  = (const float*)d_in[0];
    const float* Wq = (const float*)d_in[1];
    const float* Wk = (const float*)d_in[2];
    const float* Wv = (const float*)d_in[3];
    const float* Wo = (const float*)d_in[4];
    float* out = (float*)d_out;

    char* ws = (char*)d_ws;
    size_t off = 0;
    float*  pos   = (float*)(ws + off);  off += (size_t)SEQ * DHEAD * 4;
    ushort* xb    = (ushort*)(ws + off); off += (size_t)MROWS * EMB * 2;
    ushort* Wqkvt = (ushort*)(ws + off); off += (size_t)3072 * EMB * 2;
    ushort* Wot   = (ushort*)(ws + off); off += (size_t)EMB * EMB * 2;
    ushort* QKb   = (ushort*)(ws + off); off += (size_t)MROWS * QKS * 2;
    ushort* Vtp   = (ushort*)(ws + off); off += (size_t)MROWS * EMB * 2;
    ushort* AOb   = (ushort*)(ws + off); off += (size_t)MROWS * EMB * 2;
    const bool use_bf16 = off <= ws_size;

    const int M = MROWS, K = EMB;

    if (use_bf16) {
        // merged prep: cvt float4 (4096) | weight transpose (4096) | pos (512)
        prep_all<<<dim3(8704), 256, 0, stream>>>(
            x, Wq, Wk, Wv, Wo, xb, Wqkvt, Wot, pos);

        // fused QKV projection: Q/K -> QKb (stride 2048, +pos, Q*scl),
        // V -> Vtp transposed [bh][d][s]
        gemm_mfma_t<128><<<dim3(M / 128, 3072 / 128), 256, 0, stream>>>(
            xb, Wqkvt, QKb, Vtp, pos, 1, 3072, K);

        // 512 balanced paired blocks, XCD-affine decode, dual-tile interleave
        attn_mfma12<<<dim3(512), 256, 0, stream>>>(QKb, Vtp, AOb);

        // Wo GEMM: TM=64 -> 512 blocks (2/CU)
        gemm_mfma_t<64><<<dim3(M / 64, EMB / 128), 256, 0, stream>>>(
            AOb, Wot, out, nullptr, pos, 0, EMB, K);
    } else {
        // fp32 fallback
        size_t f = 0;
        float* posf = (float*)(ws + f); f += (size_t)SEQ * DHEAD * 4;
        float* Qb = (float*)(ws + f); f += (size_t)MROWS * EMB * 4;
        float* Kb = (float*)(ws + f); f += (size_t)MROWS * EMB * 4;
        float* Vb = (float*)(ws + f); f += (size_t)MROWS * EMB * 4;
        float* AO = (float*)(ws + f);
        pos_init<<<SEQ, DHEAD, 0, stream>>>(posf);
        dim3 g(M / BM, EMB / BN);
        gemm_f32<<<g, 256, 0, stream>>>(x, Wq, Qb, posf, 1, M, EMB, K);
        gemm_f32<<<g, 256, 0, stream>>>(x, Wk, Kb, posf, 1, M, EMB, K);
        gemm_f32<<<g, 256, 0, stream>>>(x, Wv, Vb, posf, 0, M, EMB, K);
        attn_fwd<<<dim3(SEQ / QT, BATCH * NHEAD), QT, 0, stream>>>(Qb, Kb, Vb, AO);
        gemm_f32<<<g, 256, 0, stream>>>(AO, Wo, out, posf, 0, M, EMB, K);
    }
}